// Round 1
// baseline (14965.694 us; speedup 1.0000x reference)
//
#include <hip/hip_runtime.h>
#include <math.h>

#define N_NODES 50000
#define F_IN    512
#define H1      8
#define C1      8
#define D1      64    // H1*C1
#define OUT_C   128
#define NEG     0.2f

__device__ __forceinline__ float leaky(float x){ return x > 0.f ? x : NEG*x; }

__device__ __forceinline__ void atomAddF(float* p, float v){
    unsafeAtomicAdd(p, v);   // native global_atomic_add_f32 on gfx950
}

// ---------------------------------------------------------------- init
__global__ void k_init(float* denom1, float* out1acc, float* denom2,
                       float* out, const float* __restrict__ b2){
    int i = blockIdx.x*blockDim.x + threadIdx.x;
    int stride = gridDim.x*blockDim.x;
    for (int j=i; j<N_NODES*H1;    j+=stride) denom1[j] = 0.f;
    for (int j=i; j<N_NODES*D1;    j+=stride) out1acc[j] = 0.f;
    for (int j=i; j<N_NODES;       j+=stride) denom2[j] = 0.f;
    for (int j=i; j<N_NODES*OUT_C; j+=stride) out[j] = b2[j & (OUT_C-1)];
}

// ---------------------------------------------------------------- GEMM1: h1 = x @ W1, + alpha projections
#define NPB1 8
__global__ __launch_bounds__(64) void k_gemm1(
        const float* __restrict__ x, const float* __restrict__ W1,
        const float* __restrict__ att_src, const float* __restrict__ att_dst,
        float* __restrict__ h1, float* __restrict__ asrc, float* __restrict__ adst){
    __shared__ float xs[NPB1*F_IN];          // 16 KB
    const int tid = threadIdx.x;
    const int n0  = blockIdx.x*NPB1;

    const float4* xsrc = (const float4*)(x + (size_t)n0*F_IN);
    float4* xd = (float4*)xs;
    for (int i=tid; i<NPB1*F_IN/4; i+=64) xd[i] = xsrc[i];
    __syncthreads();

    const int col = tid;                     // 0..63
    float acc[NPB1];
    #pragma unroll
    for (int i=0;i<NPB1;i++) acc[i]=0.f;

    for (int k=0;k<F_IN;k+=4){
        float4 xv[NPB1];
        #pragma unroll
        for (int i=0;i<NPB1;i++) xv[i] = *(const float4*)&xs[i*F_IN+k];
        #pragma unroll
        for (int kk=0;kk<4;kk++){
            float w = W1[(size_t)(k+kk)*D1 + col];
            #pragma unroll
            for (int i=0;i<NPB1;i++)
                acc[i] += ((const float*)&xv[i])[kk] * w;
        }
    }

    const float aw = att_src[col];           // att_src1 flat [h*8+c] == [col]
    const float dw = att_dst[col];
    #pragma unroll
    for (int i=0;i<NPB1;i++){
        h1[(size_t)(n0+i)*D1 + col] = acc[i];
        float s = acc[i]*aw, d = acc[i]*dw;
        #pragma unroll
        for (int off=1; off<8; off<<=1){
            s += __shfl_xor(s, off);
            d += __shfl_xor(d, off);
        }
        if ((col&7)==0){
            asrc[(n0+i)*H1 + (col>>3)] = s;
            adst[(n0+i)*H1 + (col>>3)] = d;
        }
    }
}

// ---------------------------------------------------------------- layer1 softmax denominator
__global__ void k_edge_denom1(const int* __restrict__ src_a, const int* __restrict__ dst_a,
        int E, const float* __restrict__ asrc, const float* __restrict__ adst,
        float* denom){
    int e = blockIdx.x*blockDim.x + threadIdx.x;
    int ET = E + N_NODES;
    if (e >= ET) return;
    int s = (e < E) ? src_a[e] : (e - E);
    int d = (e < E) ? dst_a[e] : (e - E);
    float av[8], bv[8];
    *(float4*)&av[0] = *(const float4*)(asrc + (size_t)s*H1);
    *(float4*)&av[4] = *(const float4*)(asrc + (size_t)s*H1 + 4);
    *(float4*)&bv[0] = *(const float4*)(adst + (size_t)d*H1);
    *(float4*)&bv[4] = *(const float4*)(adst + (size_t)d*H1 + 4);
    float* dn = denom + (size_t)d*H1;
    #pragma unroll
    for (int h=0; h<8; h++){
        float w = expf(leaky(av[h]+bv[h]));
        atomAddF(dn+h, w);
    }
}

// ---------------------------------------------------------------- layer1 message aggregation
__global__ void k_edge_msg1(const int* __restrict__ src_a, const int* __restrict__ dst_a,
        int E, const float* __restrict__ asrc, const float* __restrict__ adst,
        const float* __restrict__ denom, const float* __restrict__ h1,
        float* out1acc){
    int idx = blockIdx.x*blockDim.x + threadIdx.x;
    int ET = E + N_NODES;
    if (idx >= ET*H1) return;
    int e = idx >> 3, h = idx & 7;
    int s = (e < E) ? src_a[e] : (e - E);
    int d = (e < E) ? dst_a[e] : (e - E);
    float w = expf(leaky(asrc[(size_t)s*H1+h] + adst[(size_t)d*H1+h]));
    float alpha = w / denom[(size_t)d*H1+h];
    const float* hs = h1 + (size_t)s*D1 + h*C1;
    float* o = out1acc + (size_t)d*D1 + h*C1;
    float4 v0 = *(const float4*)hs;
    float4 v1 = *(const float4*)(hs+4);
    atomAddF(o+0, v0.x*alpha); atomAddF(o+1, v0.y*alpha);
    atomAddF(o+2, v0.z*alpha); atomAddF(o+3, v0.w*alpha);
    atomAddF(o+4, v1.x*alpha); atomAddF(o+5, v1.y*alpha);
    atomAddF(o+6, v1.z*alpha); atomAddF(o+7, v1.w*alpha);
}

// ---------------------------------------------------------------- GEMM2: h2 = elu(out1+b1) @ W2, + alpha projections
#define NPB2 8
__global__ __launch_bounds__(128) void k_gemm2(
        const float* __restrict__ out1acc, const float* __restrict__ b1,
        const float* __restrict__ W2,
        const float* __restrict__ att_src2, const float* __restrict__ att_dst2,
        float* __restrict__ h2, float* __restrict__ asrc2, float* __restrict__ adst2){
    __shared__ float W2s[D1*OUT_C];          // 32 KB
    __shared__ float xs[NPB2*D1];            // 2 KB
    __shared__ float red[2][NPB2][2];
    const int tid = threadIdx.x;
    const int n0  = blockIdx.x*NPB2;

    for (int i=tid; i<D1*OUT_C/4; i+=128) ((float4*)W2s)[i] = ((const float4*)W2)[i];
    for (int i=tid; i<NPB2*D1; i+=128){
        int c = i & (D1-1);
        float v = out1acc[(size_t)n0*D1 + i] + b1[c];
        xs[i] = v > 0.f ? v : (expf(v) - 1.f);   // ELU
    }
    __syncthreads();

    const int col = tid;                     // 0..127
    float acc[NPB2];
    #pragma unroll
    for (int i=0;i<NPB2;i++) acc[i]=0.f;
    for (int k=0;k<D1;k++){
        float w = W2s[k*OUT_C + col];
        #pragma unroll
        for (int i=0;i<NPB2;i++) acc[i] += xs[i*D1+k]*w;
    }

    const float aw = att_src2[col], dw = att_dst2[col];
    const int wv = tid >> 6, lane = tid & 63;
    #pragma unroll
    for (int i=0;i<NPB2;i++){
        h2[(size_t)(n0+i)*OUT_C + col] = acc[i];
        float s = acc[i]*aw, d = acc[i]*dw;
        #pragma unroll
        for (int off=1; off<64; off<<=1){
            s += __shfl_xor(s, off);
            d += __shfl_xor(d, off);
        }
        if (lane == 0){ red[wv][i][0]=s; red[wv][i][1]=d; }
    }
    __syncthreads();
    if (tid < NPB2){
        asrc2[n0+tid] = red[0][tid][0] + red[1][tid][0];
        adst2[n0+tid] = red[0][tid][1] + red[1][tid][1];
    }
}

// ---------------------------------------------------------------- layer2 softmax denominator
__global__ void k_edge_denom2(const int* __restrict__ src_a, const int* __restrict__ dst_a,
        int E, const float* __restrict__ asrc2, const float* __restrict__ adst2,
        float* denom2){
    int e = blockIdx.x*blockDim.x + threadIdx.x;
    int ET = E + N_NODES;
    if (e >= ET) return;
    int s = (e < E) ? src_a[e] : (e - E);
    int d = (e < E) ? dst_a[e] : (e - E);
    float w = expf(leaky(asrc2[s] + adst2[d]));
    atomAddF(denom2 + d, w);
}

// ---------------------------------------------------------------- layer2 message aggregation -> d_out
__global__ void k_edge_msg2(const int* __restrict__ src_a, const int* __restrict__ dst_a,
        int E, const float* __restrict__ asrc2, const float* __restrict__ adst2,
        const float* __restrict__ denom2, const float* __restrict__ h2,
        float* out){
    int idx = blockIdx.x*blockDim.x + threadIdx.x;
    int ET = E + N_NODES;
    if (idx >= ET*4) return;
    int e = idx >> 2, q = idx & 3;
    int s = (e < E) ? src_a[e] : (e - E);
    int d = (e < E) ? dst_a[e] : (e - E);
    float alpha = expf(leaky(asrc2[s] + adst2[d])) / denom2[d];
    const float4* hs = (const float4*)(h2 + (size_t)s*OUT_C + q*32);
    float* o = out + (size_t)d*OUT_C + q*32;
    #pragma unroll
    for (int c4=0;c4<8;c4++){
        float4 v = hs[c4];
        atomAddF(o + c4*4 + 0, v.x*alpha);
        atomAddF(o + c4*4 + 1, v.y*alpha);
        atomAddF(o + c4*4 + 2, v.z*alpha);
        atomAddF(o + c4*4 + 3, v.w*alpha);
    }
}

// ---------------------------------------------------------------- launch
extern "C" void kernel_launch(void* const* d_in, const int* in_sizes, int n_in,
                              void* d_out, int out_size, void* d_ws, size_t ws_size,
                              hipStream_t stream) {
    const float* x        = (const float*)d_in[0];
    const int*   edge     = (const int*)  d_in[1];
    const float* W1       = (const float*)d_in[2];
    const float* att_src1 = (const float*)d_in[3];
    const float* att_dst1 = (const float*)d_in[4];
    const float* b1       = (const float*)d_in[5];
    const float* W2       = (const float*)d_in[6];
    const float* att_src2 = (const float*)d_in[7];
    const float* att_dst2 = (const float*)d_in[8];
    const float* b2       = (const float*)d_in[9];
    float* out = (float*)d_out;

    const int E = in_sizes[1] / 2;
    const int ET = E + N_NODES;
    const int* src_a = edge;
    const int* dst_a = edge + E;

    // workspace layout (floats)
    float* ws = (float*)d_ws;
    float* h1      = ws;                         // N*64
    float* asrc1   = h1    + (size_t)N_NODES*D1; // N*8
    float* adst1   = asrc1 + (size_t)N_NODES*H1;
    float* denom1  = adst1 + (size_t)N_NODES*H1;
    float* out1acc = denom1+ (size_t)N_NODES*H1; // N*64
    float* h2      = out1acc+(size_t)N_NODES*D1; // N*128
    float* asrc2   = h2    + (size_t)N_NODES*OUT_C;
    float* adst2   = asrc2 + N_NODES;
    float* denom2  = adst2 + N_NODES;

    hipLaunchKernelGGL(k_init, dim3(2048), dim3(256), 0, stream,
                       denom1, out1acc, denom2, out, b2);

    hipLaunchKernelGGL(k_gemm1, dim3(N_NODES/NPB1), dim3(64), 0, stream,
                       x, W1, att_src1, att_dst1, h1, asrc1, adst1);

    hipLaunchKernelGGL(k_edge_denom1, dim3((ET+255)/256), dim3(256), 0, stream,
                       src_a, dst_a, E, asrc1, adst1, denom1);

    hipLaunchKernelGGL(k_edge_msg1, dim3((ET*H1+255)/256), dim3(256), 0, stream,
                       src_a, dst_a, E, asrc1, adst1, denom1, h1, out1acc);

    hipLaunchKernelGGL(k_gemm2, dim3(N_NODES/NPB2), dim3(128), 0, stream,
                       out1acc, b1, W2, att_src2, att_dst2, h2, asrc2, adst2);

    hipLaunchKernelGGL(k_edge_denom2, dim3((ET+255)/256), dim3(256), 0, stream,
                       src_a, dst_a, E, asrc2, adst2, denom2);

    hipLaunchKernelGGL(k_edge_msg2, dim3((ET*4+255)/256), dim3(256), 0, stream,
                       src_a, dst_a, E, asrc2, adst2, denom2, h2, out);
}

// Round 2
// 803.726 us; speedup vs baseline: 18.6204x; 18.6204x over previous
//
#include <hip/hip_runtime.h>
#include <math.h>

#define N_NODES 50000
#define F_IN    512
#define H1      8
#define C1      8
#define D1      64    // H1*C1
#define OUT_C   128
#define NEG     0.2f

__device__ __forceinline__ float leaky(float x){ return x > 0.f ? x : NEG*x; }

// ---------------------------------------------------------------- zero/init counts (self-loop => start at 1)
__global__ void k_zero_cnt(int* cnt){
    int i = blockIdx.x*blockDim.x + threadIdx.x;
    if (i < N_NODES) cnt[i] = 1;
}

// ---------------------------------------------------------------- histogram of real edges by dst
__global__ void k_hist(const int* __restrict__ dst_a, int E, int* cnt){
    int i = blockIdx.x*blockDim.x + threadIdx.x;
    if (i >= E) return;
    atomicAdd(cnt + dst_a[i], 1);
}

// ---------------------------------------------------------------- single-block exclusive scan (50000 -> rowptr, cur)
__global__ __launch_bounds__(1024) void k_scan(const int* __restrict__ cnt,
                                               int* rowptr, int* cur){
    __shared__ int part[1024];
    const int tid = threadIdx.x;
    const int PER = (N_NODES + 1023) / 1024;   // 49
    const int base = tid * PER;
    int sum = 0;
    for (int i=0;i<PER;i++){ int idx=base+i; if (idx<N_NODES) sum += cnt[idx]; }
    part[tid] = sum; __syncthreads();
    for (int off=1; off<1024; off<<=1){
        int v = (tid>=off) ? part[tid-off] : 0;
        __syncthreads();
        part[tid] += v;
        __syncthreads();
    }
    int prefix = (tid==0) ? 0 : part[tid-1];
    for (int i=0;i<PER;i++){
        int idx=base+i;
        if (idx<N_NODES){
            rowptr[idx]=prefix; cur[idx]=prefix;
            prefix += cnt[idx];
        }
    }
    if (tid==0) rowptr[N_NODES] = part[1023];
}

// ---------------------------------------------------------------- scatter edges (and self-loops) into CSR src list
__global__ void k_scatter(const int* __restrict__ src_a, const int* __restrict__ dst_a,
                          int E, int* cur, int* srcs){
    int i = blockIdx.x*blockDim.x + threadIdx.x;
    int ET = E + N_NODES;
    if (i >= ET) return;
    int s, d;
    if (i < E){ s = src_a[i]; d = dst_a[i]; }
    else      { s = d = i - E; }
    int pos = atomicAdd(cur + d, 1);
    srcs[pos] = s;
}

// ---------------------------------------------------------------- GEMM1: h1 = x @ W1, + alpha projections
#define NPB1 8
__global__ __launch_bounds__(64) void k_gemm1(
        const float* __restrict__ x, const float* __restrict__ W1,
        const float* __restrict__ att_src, const float* __restrict__ att_dst,
        float* __restrict__ h1, float* __restrict__ asrc, float* __restrict__ adst){
    __shared__ float xs[NPB1*F_IN];          // 16 KB
    const int tid = threadIdx.x;
    const int n0  = blockIdx.x*NPB1;

    const float4* xsrc = (const float4*)(x + (size_t)n0*F_IN);
    float4* xd = (float4*)xs;
    for (int i=tid; i<NPB1*F_IN/4; i+=64) xd[i] = xsrc[i];
    __syncthreads();

    const int col = tid;                     // 0..63
    float acc[NPB1];
    #pragma unroll
    for (int i=0;i<NPB1;i++) acc[i]=0.f;

    for (int k=0;k<F_IN;k+=4){
        float4 xv[NPB1];
        #pragma unroll
        for (int i=0;i<NPB1;i++) xv[i] = *(const float4*)&xs[i*F_IN+k];
        #pragma unroll
        for (int kk=0;kk<4;kk++){
            float w = W1[(size_t)(k+kk)*D1 + col];
            #pragma unroll
            for (int i=0;i<NPB1;i++)
                acc[i] += ((const float*)&xv[i])[kk] * w;
        }
    }

    const float aw = att_src[col];           // att_src1 flat [h*8+c] == [col]
    const float dw = att_dst[col];
    #pragma unroll
    for (int i=0;i<NPB1;i++){
        h1[(size_t)(n0+i)*D1 + col] = acc[i];
        float s = acc[i]*aw, d = acc[i]*dw;
        #pragma unroll
        for (int off=1; off<8; off<<=1){
            s += __shfl_xor(s, off);
            d += __shfl_xor(d, off);
        }
        if ((col&7)==0){
            asrc[(n0+i)*H1 + (col>>3)] = s;
            adst[(n0+i)*H1 + (col>>3)] = d;
        }
    }
}

// ---------------------------------------------------------------- layer1 aggregation: one wave per node
// out1[n][ch] = (sum_e w_e * h1[src_e][ch]) / (sum_e w_e),  w = exp(leaky(asrc[s][h]+adst[n][h]))
__global__ __launch_bounds__(256) void k_agg1(
        const int* __restrict__ rowptr, const int* __restrict__ srcs,
        const float* __restrict__ asrc1, const float* __restrict__ adst1,
        const float* __restrict__ h1, float* __restrict__ out1){
    const int node = blockIdx.x*4 + (threadIdx.x>>6);
    if (node >= N_NODES) return;
    const int lane = threadIdx.x & 63;
    const int h    = lane >> 3;
    const int r0 = rowptr[node], r1 = rowptr[node+1];
    const float ad = adst1[node*H1 + h];
    float acc = 0.f, den = 0.f;
    for (int base=r0; base<r1; base+=64){
        const int n = min(64, r1-base);
        int sl = (base+lane < r1) ? srcs[base+lane] : 0;
        for (int j=0; j<n; j++){
            int s = __shfl(sl, j);
            float as = asrc1[s*H1 + h];
            float w  = expf(leaky(as + ad));
            acc += w * h1[(size_t)s*D1 + lane];
            den += w;
        }
    }
    out1[(size_t)node*D1 + lane] = acc/den;
}

// ---------------------------------------------------------------- GEMM2: h2 = elu(out1+b1) @ W2, + alpha projections
#define NPB2 8
__global__ __launch_bounds__(128) void k_gemm2(
        const float* __restrict__ out1, const float* __restrict__ b1,
        const float* __restrict__ W2,
        const float* __restrict__ att_src2, const float* __restrict__ att_dst2,
        float* __restrict__ h2, float* __restrict__ asrc2, float* __restrict__ adst2){
    __shared__ float W2s[D1*OUT_C];          // 32 KB
    __shared__ float xs[NPB2*D1];            // 2 KB
    __shared__ float red[2][NPB2][2];
    const int tid = threadIdx.x;
    const int n0  = blockIdx.x*NPB2;

    for (int i=tid; i<D1*OUT_C/4; i+=128) ((float4*)W2s)[i] = ((const float4*)W2)[i];
    for (int i=tid; i<NPB2*D1; i+=128){
        int c = i & (D1-1);
        float v = out1[(size_t)n0*D1 + i] + b1[c];
        xs[i] = v > 0.f ? v : (expf(v) - 1.f);   // ELU
    }
    __syncthreads();

    const int col = tid;                     // 0..127
    float acc[NPB2];
    #pragma unroll
    for (int i=0;i<NPB2;i++) acc[i]=0.f;
    for (int k=0;k<D1;k++){
        float w = W2s[k*OUT_C + col];
        #pragma unroll
        for (int i=0;i<NPB2;i++) acc[i] += xs[i*D1+k]*w;
    }

    const float aw = att_src2[col], dw = att_dst2[col];
    const int wv = tid >> 6, lane = tid & 63;
    #pragma unroll
    for (int i=0;i<NPB2;i++){
        h2[(size_t)(n0+i)*OUT_C + col] = acc[i];
        float s = acc[i]*aw, d = acc[i]*dw;
        #pragma unroll
        for (int off=1; off<64; off<<=1){
            s += __shfl_xor(s, off);
            d += __shfl_xor(d, off);
        }
        if (lane == 0){ red[wv][i][0]=s; red[wv][i][1]=d; }
    }
    __syncthreads();
    if (tid < NPB2){
        asrc2[n0+tid] = red[0][tid][0] + red[1][tid][0];
        adst2[n0+tid] = red[0][tid][1] + red[1][tid][1];
    }
}

// ---------------------------------------------------------------- layer2 aggregation: 128 threads per node (2 waves)
__global__ __launch_bounds__(256) void k_agg2(
        const int* __restrict__ rowptr, const int* __restrict__ srcs,
        const float* __restrict__ asrc2, const float* __restrict__ adst2,
        const float* __restrict__ h2, const float* __restrict__ b2,
        float* __restrict__ out){
    const int node = blockIdx.x*2 + (threadIdx.x>>7);
    if (node >= N_NODES) return;
    const int c    = threadIdx.x & 127;
    const int lane = threadIdx.x & 63;
    const int r0 = rowptr[node], r1 = rowptr[node+1];
    const float ad = adst2[node];
    float acc = 0.f, den = 0.f;
    for (int base=r0; base<r1; base+=64){
        const int n = min(64, r1-base);
        int sl = (base+lane < r1) ? srcs[base+lane] : 0;
        for (int j=0; j<n; j++){
            int s = __shfl(sl, j);
            float w = expf(leaky(asrc2[s] + ad));
            acc += w * h2[(size_t)s*OUT_C + c];
            den += w;
        }
    }
    out[(size_t)node*OUT_C + c] = acc/den + b2[c];
}

// ---------------------------------------------------------------- launch
extern "C" void kernel_launch(void* const* d_in, const int* in_sizes, int n_in,
                              void* d_out, int out_size, void* d_ws, size_t ws_size,
                              hipStream_t stream) {
    const float* x        = (const float*)d_in[0];
    const int*   edge     = (const int*)  d_in[1];
    const float* W1       = (const float*)d_in[2];
    const float* att_src1 = (const float*)d_in[3];
    const float* att_dst1 = (const float*)d_in[4];
    const float* b1       = (const float*)d_in[5];
    const float* W2       = (const float*)d_in[6];
    const float* att_src2 = (const float*)d_in[7];
    const float* att_dst2 = (const float*)d_in[8];
    const float* b2       = (const float*)d_in[9];
    float* out = (float*)d_out;

    const int E  = in_sizes[1] / 2;
    const int ET = E + N_NODES;
    const int* src_a = edge;
    const int* dst_a = edge + E;

    // workspace layout
    float* ws = (float*)d_ws;
    float* h1    = ws;                          // N*64
    float* asrc1 = h1    + (size_t)N_NODES*D1;  // N*8
    float* adst1 = asrc1 + (size_t)N_NODES*H1;  // N*8
    float* out1  = adst1 + (size_t)N_NODES*H1;  // N*64
    float* h2    = out1  + (size_t)N_NODES*D1;  // N*128
    float* asrc2 = h2    + (size_t)N_NODES*OUT_C; // N
    float* adst2 = asrc2 + N_NODES;             // N
    int*   cnt    = (int*)(adst2 + N_NODES);    // N
    int*   rowptr = cnt    + N_NODES;           // N+1
    int*   cur    = rowptr + (N_NODES+1);       // N
    int*   srcs   = cur    + N_NODES;           // ET

    // ---- CSR build (counting sort by dst)
    hipLaunchKernelGGL(k_zero_cnt, dim3((N_NODES+255)/256), dim3(256), 0, stream, cnt);
    hipLaunchKernelGGL(k_hist,    dim3((E+255)/256), dim3(256), 0, stream, dst_a, E, cnt);
    hipLaunchKernelGGL(k_scan,    dim3(1), dim3(1024), 0, stream, cnt, rowptr, cur);
    hipLaunchKernelGGL(k_scatter, dim3((ET+255)/256), dim3(256), 0, stream,
                       src_a, dst_a, E, cur, srcs);

    // ---- layer 1
    hipLaunchKernelGGL(k_gemm1, dim3(N_NODES/NPB1), dim3(64), 0, stream,
                       x, W1, att_src1, att_dst1, h1, asrc1, adst1);
    hipLaunchKernelGGL(k_agg1,  dim3((N_NODES+3)/4), dim3(256), 0, stream,
                       rowptr, srcs, asrc1, adst1, h1, out1);

    // ---- layer 2
    hipLaunchKernelGGL(k_gemm2, dim3(N_NODES/NPB2), dim3(128), 0, stream,
                       out1, b1, W2, att_src2, att_dst2, h2, asrc2, adst2);
    hipLaunchKernelGGL(k_agg2,  dim3((N_NODES+1)/2), dim3(256), 0, stream,
                       rowptr, srcs, asrc2, adst2, h2, b2, out);
}

// Round 3
// 786.938 us; speedup vs baseline: 19.0176x; 1.0213x over previous
//
#include <hip/hip_runtime.h>
#include <math.h>

#define N_NODES 50000
#define F_IN    512
#define H1      8
#define C1      8
#define D1      64    // H1*C1
#define OUT_C   128
#define NEG     0.2f

__device__ __forceinline__ float leaky(float x){
    return fmaxf(x, 0.f) + NEG * fminf(x, 0.f);
}

// ---------------------------------------------------------------- zero/init counts (self-loop => start at 1)
__global__ void k_zero_cnt(int* cnt){
    int i = blockIdx.x*blockDim.x + threadIdx.x;
    if (i < N_NODES) cnt[i] = 1;
}

// ---------------------------------------------------------------- histogram of real edges by dst
__global__ void k_hist(const int* __restrict__ dst_a, int E, int* cnt){
    int i = blockIdx.x*blockDim.x + threadIdx.x;
    if (i >= E) return;
    atomicAdd(cnt + dst_a[i], 1);
}

// ---------------------------------------------------------------- single-block exclusive scan (50000 -> rowptr, cur)
__global__ __launch_bounds__(1024) void k_scan(const int* __restrict__ cnt,
                                               int* rowptr, int* cur){
    __shared__ int part[1024];
    const int tid = threadIdx.x;
    const int PER = (N_NODES + 1023) / 1024;   // 49
    const int base = tid * PER;
    int sum = 0;
    for (int i=0;i<PER;i++){ int idx=base+i; if (idx<N_NODES) sum += cnt[idx]; }
    part[tid] = sum; __syncthreads();
    for (int off=1; off<1024; off<<=1){
        int v = (tid>=off) ? part[tid-off] : 0;
        __syncthreads();
        part[tid] += v;
        __syncthreads();
    }
    int prefix = (tid==0) ? 0 : part[tid-1];
    for (int i=0;i<PER;i++){
        int idx=base+i;
        if (idx<N_NODES){
            rowptr[idx]=prefix; cur[idx]=prefix;
            prefix += cnt[idx];
        }
    }
    if (tid==0) rowptr[N_NODES] = part[1023];
}

// ---------------------------------------------------------------- scatter edges (and self-loops) into CSR src list
__global__ void k_scatter(const int* __restrict__ src_a, const int* __restrict__ dst_a,
                          int E, int* cur, int* srcs){
    int i = blockIdx.x*blockDim.x + threadIdx.x;
    int ET = E + N_NODES;
    if (i >= ET) return;
    int s, d;
    if (i < E){ s = src_a[i]; d = dst_a[i]; }
    else      { s = d = i - E; }
    int pos = atomicAdd(cur + d, 1);
    srcs[pos] = s;
}

// ---------------------------------------------------------------- GEMM1: h1 = x @ W1, + alpha projections
#define NPB1 8
__global__ __launch_bounds__(64) void k_gemm1(
        const float* __restrict__ x, const float* __restrict__ W1,
        const float* __restrict__ att_src, const float* __restrict__ att_dst,
        float* __restrict__ h1, float* __restrict__ asrc, float* __restrict__ adst){
    __shared__ float xs[NPB1*F_IN];          // 16 KB
    const int tid = threadIdx.x;
    const int n0  = blockIdx.x*NPB1;

    const float4* xsrc = (const float4*)(x + (size_t)n0*F_IN);
    float4* xd = (float4*)xs;
    for (int i=tid; i<NPB1*F_IN/4; i+=64) xd[i] = xsrc[i];
    __syncthreads();

    const int col = tid;                     // 0..63
    float acc[NPB1];
    #pragma unroll
    for (int i=0;i<NPB1;i++) acc[i]=0.f;

    for (int k=0;k<F_IN;k+=4){
        float4 xv[NPB1];
        #pragma unroll
        for (int i=0;i<NPB1;i++) xv[i] = *(const float4*)&xs[i*F_IN+k];
        #pragma unroll
        for (int kk=0;kk<4;kk++){
            float w = W1[(size_t)(k+kk)*D1 + col];
            #pragma unroll
            for (int i=0;i<NPB1;i++)
                acc[i] += ((const float*)&xv[i])[kk] * w;
        }
    }

    const float aw = att_src[col];           // att_src1 flat [h*8+c] == [col]
    const float dw = att_dst[col];
    #pragma unroll
    for (int i=0;i<NPB1;i++){
        h1[(size_t)(n0+i)*D1 + col] = acc[i];
        float s = acc[i]*aw, d = acc[i]*dw;
        #pragma unroll
        for (int off=1; off<8; off<<=1){
            s += __shfl_xor(s, off);
            d += __shfl_xor(d, off);
        }
        if ((col&7)==0){
            asrc[(n0+i)*H1 + (col>>3)] = s;
            adst[(n0+i)*H1 + (col>>3)] = d;
        }
    }
}

// ---------------------------------------------------------------- layer1 aggregation: one wave per node
// lane c = channel 0..63, head h=c>>3.
// weights precomputed lane-parallel: lane L -> edge (L>>3), head (L&7)
__global__ __launch_bounds__(256) void k_agg1(
        const int* __restrict__ rowptr, const int* __restrict__ srcs,
        const float* __restrict__ asrc1, const float* __restrict__ adst1,
        const float* __restrict__ h1, float* __restrict__ out1){
    const int node = blockIdx.x*4 + (threadIdx.x>>6);
    if (node >= N_NODES) return;
    const int c    = threadIdx.x & 63;
    const int h    = c >> 3;
    const int idx8 = c >> 3;     // edge-slot for weight compute
    const int hh   = c & 7;      // head for weight compute
    const int r0 = rowptr[node], r1 = rowptr[node+1];
    const float ad_w = adst1[node*H1 + hh];   // dst term for weight lane
    const int wsel = (c >> 3);                // head index used in accumulation

    float acc = 0.f, den = 0.f;
    for (int base=r0; base<r1; base+=8){
        const int nb = min(8, r1-base);
        int eidx = base + idx8;
        int sl = srcs[eidx < r1 ? eidx : (r1-1)];
        float w_l = __expf(leaky(asrc1[sl*H1 + hh] + ad_w));
        #pragma unroll 4
        for (int j=0; j<nb; j++){
            int   s = __shfl(sl,  j*8);
            float w = __shfl(w_l, j*8 + wsel);
            acc += w * h1[(size_t)s*D1 + c];
            den += w;
        }
    }
    out1[(size_t)node*D1 + c] = acc/den;
}

// ---------------------------------------------------------------- GEMM2: h2 = elu(out1+b1) @ W2, + alpha projections
#define NPB2 8
__global__ __launch_bounds__(128) void k_gemm2(
        const float* __restrict__ out1, const float* __restrict__ b1,
        const float* __restrict__ W2,
        const float* __restrict__ att_src2, const float* __restrict__ att_dst2,
        float* __restrict__ h2, float* __restrict__ asrc2, float* __restrict__ adst2){
    __shared__ float W2s[D1*OUT_C];          // 32 KB
    __shared__ float xs[NPB2*D1];            // 2 KB
    __shared__ float red[2][NPB2][2];
    const int tid = threadIdx.x;
    const int n0  = blockIdx.x*NPB2;

    for (int i=tid; i<D1*OUT_C/4; i+=128) ((float4*)W2s)[i] = ((const float4*)W2)[i];
    for (int i=tid; i<NPB2*D1; i+=128){
        int c = i & (D1-1);
        float v = out1[(size_t)n0*D1 + i] + b1[c];
        xs[i] = v > 0.f ? v : (__expf(v) - 1.f);   // ELU
    }
    __syncthreads();

    const int col = tid;                     // 0..127
    float acc[NPB2];
    #pragma unroll
    for (int i=0;i<NPB2;i++) acc[i]=0.f;
    for (int k=0;k<D1;k++){
        float w = W2s[k*OUT_C + col];
        #pragma unroll
        for (int i=0;i<NPB2;i++) acc[i] += xs[i*D1+k]*w;
    }

    const float aw = att_src2[col], dw = att_dst2[col];
    const int wv = tid >> 6, lane = tid & 63;
    #pragma unroll
    for (int i=0;i<NPB2;i++){
        h2[(size_t)(n0+i)*OUT_C + col] = acc[i];
        float s = acc[i]*aw, d = acc[i]*dw;
        #pragma unroll
        for (int off=1; off<64; off<<=1){
            s += __shfl_xor(s, off);
            d += __shfl_xor(d, off);
        }
        if (lane == 0){ red[wv][i][0]=s; red[wv][i][1]=d; }
    }
    __syncthreads();
    if (tid < NPB2){
        asrc2[n0+tid] = red[0][tid][0] + red[1][tid][0];
        adst2[n0+tid] = red[0][tid][1] + red[1][tid][1];
    }
}

// ---------------------------------------------------------------- layer2 aggregation: 128 threads per node (2 waves)
// each wave precomputes 64 edge-weights lane-parallel, then broadcast via shfl
__global__ __launch_bounds__(256) void k_agg2(
        const int* __restrict__ rowptr, const int* __restrict__ srcs,
        const float* __restrict__ asrc2, const float* __restrict__ adst2,
        const float* __restrict__ h2, const float* __restrict__ b2,
        float* __restrict__ out){
    const int node = blockIdx.x*2 + (threadIdx.x>>7);
    if (node >= N_NODES) return;
    const int c    = threadIdx.x & 127;
    const int lane = threadIdx.x & 63;
    const int r0 = rowptr[node], r1 = rowptr[node+1];
    const float ad = adst2[node];
    float acc = 0.f, den = 0.f;
    for (int base=r0; base<r1; base+=64){
        const int n = min(64, r1-base);
        int eidx = base + lane;
        int sl = srcs[eidx < r1 ? eidx : (r1-1)];
        float w_l = __expf(leaky(asrc2[sl] + ad));
        #pragma unroll 4
        for (int j=0; j<n; j++){
            int   s = __shfl(sl,  j);
            float w = __shfl(w_l, j);
            acc += w * h2[(size_t)s*OUT_C + c];
            den += w;
        }
    }
    out[(size_t)node*OUT_C + c] = acc/den + b2[c];
}

// ---------------------------------------------------------------- launch
extern "C" void kernel_launch(void* const* d_in, const int* in_sizes, int n_in,
                              void* d_out, int out_size, void* d_ws, size_t ws_size,
                              hipStream_t stream) {
    const float* x        = (const float*)d_in[0];
    const int*   edge     = (const int*)  d_in[1];
    const float* W1       = (const float*)d_in[2];
    const float* att_src1 = (const float*)d_in[3];
    const float* att_dst1 = (const float*)d_in[4];
    const float* b1       = (const float*)d_in[5];
    const float* W2       = (const float*)d_in[6];
    const float* att_src2 = (const float*)d_in[7];
    const float* att_dst2 = (const float*)d_in[8];
    const float* b2       = (const float*)d_in[9];
    float* out = (float*)d_out;

    const int E  = in_sizes[1] / 2;
    const int ET = E + N_NODES;
    const int* src_a = edge;
    const int* dst_a = edge + E;

    // workspace layout
    float* ws = (float*)d_ws;
    float* h1    = ws;                          // N*64
    float* asrc1 = h1    + (size_t)N_NODES*D1;  // N*8
    float* adst1 = asrc1 + (size_t)N_NODES*H1;  // N*8
    float* out1  = adst1 + (size_t)N_NODES*H1;  // N*64
    float* h2    = out1  + (size_t)N_NODES*D1;  // N*128
    float* asrc2 = h2    + (size_t)N_NODES*OUT_C; // N
    float* adst2 = asrc2 + N_NODES;             // N
    int*   cnt    = (int*)(adst2 + N_NODES);    // N
    int*   rowptr = cnt    + N_NODES;           // N+1
    int*   cur    = rowptr + (N_NODES+1);       // N
    int*   srcs   = cur    + N_NODES;           // ET

    // ---- CSR build (counting sort by dst)
    hipLaunchKernelGGL(k_zero_cnt, dim3((N_NODES+255)/256), dim3(256), 0, stream, cnt);
    hipLaunchKernelGGL(k_hist,    dim3((E+255)/256), dim3(256), 0, stream, dst_a, E, cnt);
    hipLaunchKernelGGL(k_scan,    dim3(1), dim3(1024), 0, stream, cnt, rowptr, cur);
    hipLaunchKernelGGL(k_scatter, dim3((ET+255)/256), dim3(256), 0, stream,
                       src_a, dst_a, E, cur, srcs);

    // ---- layer 1
    hipLaunchKernelGGL(k_gemm1, dim3(N_NODES/NPB1), dim3(64), 0, stream,
                       x, W1, att_src1, att_dst1, h1, asrc1, adst1);
    hipLaunchKernelGGL(k_agg1,  dim3((N_NODES+3)/4), dim3(256), 0, stream,
                       rowptr, srcs, asrc1, adst1, h1, out1);

    // ---- layer 2
    hipLaunchKernelGGL(k_gemm2, dim3(N_NODES/NPB2), dim3(128), 0, stream,
                       out1, b1, W2, att_src2, att_dst2, h2, asrc2, adst2);
    hipLaunchKernelGGL(k_agg2,  dim3((N_NODES+1)/2), dim3(256), 0, stream,
                       rowptr, srcs, asrc2, adst2, h2, b2, out);
}

// Round 4
// 557.969 us; speedup vs baseline: 26.8217x; 1.4104x over previous
//
#include <hip/hip_runtime.h>
#include <math.h>

#define N_NODES 50000
#define F_IN    512
#define H1      8
#define C1      8
#define D1      64    // H1*C1
#define OUT_C   128
#define NEG     0.2f

#define SCHUNK  256
#define SNBLK   ((N_NODES + SCHUNK - 1)/SCHUNK)   // 196

__device__ __forceinline__ float leaky(float x){
    return fmaxf(x, 0.f) + NEG * fminf(x, 0.f);
}

// ---------------------------------------------------------------- counts (self-loop => start at 1)
__global__ void k_zero_cnt(int* cnt){
    int i = blockIdx.x*blockDim.x + threadIdx.x;
    if (i < N_NODES) cnt[i] = 1;
}

__global__ void k_hist(const int* __restrict__ dst_a, int E, int* cnt){
    int i = blockIdx.x*blockDim.x + threadIdx.x;
    if (i >= E) return;
    atomicAdd(cnt + dst_a[i], 1);
}

// ---------------------------------------------------------------- 3-phase scan
__global__ __launch_bounds__(256) void k_scanA(const int* __restrict__ cnt, int* bsum){
    __shared__ int sm[256];
    int idx = blockIdx.x*256 + threadIdx.x;
    int v = (idx < N_NODES) ? cnt[idx] : 0;
    sm[threadIdx.x] = v; __syncthreads();
    for (int off=128; off>0; off>>=1){
        if (threadIdx.x < off) sm[threadIdx.x] += sm[threadIdx.x+off];
        __syncthreads();
    }
    if (threadIdx.x==0) bsum[blockIdx.x] = sm[0];
}

__global__ __launch_bounds__(256) void k_scanB(const int* __restrict__ bsum, int* boff, int* rowptr){
    __shared__ int sm[256];
    int t = threadIdx.x;
    int v = (t < SNBLK) ? bsum[t] : 0;
    sm[t]=v; __syncthreads();
    for (int off=1; off<256; off<<=1){
        int u = (t>=off)? sm[t-off] : 0;
        __syncthreads();
        sm[t]+=u; __syncthreads();
    }
    if (t < SNBLK) boff[t] = sm[t] - v;       // exclusive
    if (t==255) rowptr[N_NODES] = sm[255];    // total = E + N
}

__global__ __launch_bounds__(256) void k_scanC(const int* __restrict__ cnt, const int* __restrict__ boff,
                                               int* rowptr, int* cur){
    __shared__ int sm[256];
    int idx = blockIdx.x*256 + threadIdx.x;
    int t = threadIdx.x;
    int v = (idx<N_NODES)? cnt[idx] : 0;
    sm[t]=v; __syncthreads();
    for (int off=1; off<256; off<<=1){
        int u = (t>=off)? sm[t-off] : 0;
        __syncthreads();
        sm[t]+=u; __syncthreads();
    }
    if (idx<N_NODES){
        int ex = boff[blockIdx.x] + sm[t] - v;
        rowptr[idx]=ex; cur[idx]=ex;
    }
}

// ---------------------------------------------------------------- scatter edges + self-loops into CSR (src AND dst per slot)
__global__ void k_scatter(const int* __restrict__ src_a, const int* __restrict__ dst_a,
                          int E, int* cur, int* srcs, int* dsts){
    int i = blockIdx.x*blockDim.x + threadIdx.x;
    int ET = E + N_NODES;
    if (i >= ET) return;
    int s, d;
    if (i < E){ s = src_a[i]; d = dst_a[i]; }
    else      { s = d = i - E; }
    int pos = atomicAdd(cur + d, 1);
    srcs[pos] = s; dsts[pos] = d;
}

// ---------------------------------------------------------------- GEMM1: h1 = x @ W1, + alpha projections
#define NPB1 8
__global__ __launch_bounds__(64) void k_gemm1(
        const float* __restrict__ x, const float* __restrict__ W1,
        const float* __restrict__ att_src, const float* __restrict__ att_dst,
        float* __restrict__ h1, float* __restrict__ asrc, float* __restrict__ adst){
    __shared__ float xs[NPB1*F_IN];          // 16 KB
    const int tid = threadIdx.x;
    const int n0  = blockIdx.x*NPB1;

    const float4* xsrc = (const float4*)(x + (size_t)n0*F_IN);
    float4* xd = (float4*)xs;
    for (int i=tid; i<NPB1*F_IN/4; i+=64) xd[i] = xsrc[i];
    __syncthreads();

    const int col = tid;                     // 0..63
    float acc[NPB1];
    #pragma unroll
    for (int i=0;i<NPB1;i++) acc[i]=0.f;

    for (int k=0;k<F_IN;k+=4){
        float4 xv[NPB1];
        #pragma unroll
        for (int i=0;i<NPB1;i++) xv[i] = *(const float4*)&xs[i*F_IN+k];
        #pragma unroll
        for (int kk=0;kk<4;kk++){
            float w = W1[(size_t)(k+kk)*D1 + col];
            #pragma unroll
            for (int i=0;i<NPB1;i++)
                acc[i] += ((const float*)&xv[i])[kk] * w;
        }
    }

    const float aw = att_src[col];
    const float dw = att_dst[col];
    #pragma unroll
    for (int i=0;i<NPB1;i++){
        h1[(size_t)(n0+i)*D1 + col] = acc[i];
        float s = acc[i]*aw, d = acc[i]*dw;
        #pragma unroll
        for (int off=1; off<8; off<<=1){
            s += __shfl_xor(s, off);
            d += __shfl_xor(d, off);
        }
        if ((col&7)==0){
            asrc[(n0+i)*H1 + (col>>3)] = s;
            adst[(n0+i)*H1 + (col>>3)] = d;
        }
    }
}

// ---------------------------------------------------------------- layer1 edge weights (edge-parallel, coalesced)
__global__ void k_w1(const int* __restrict__ srcs, const int* __restrict__ dsts, int ET,
                     const float* __restrict__ asrc1, const float* __restrict__ adst1,
                     float* __restrict__ w1){
    int e = blockIdx.x*blockDim.x + threadIdx.x;
    if (e >= ET) return;
    int s = srcs[e], d = dsts[e];
    const float4* A = (const float4*)(asrc1 + (size_t)s*H1);
    const float4* B = (const float4*)(adst1 + (size_t)d*H1);
    float4 a0=A[0], a1=A[1], b0=B[0], b1=B[1];
    float4 o0, o1;
    o0.x=__expf(leaky(a0.x+b0.x)); o0.y=__expf(leaky(a0.y+b0.y));
    o0.z=__expf(leaky(a0.z+b0.z)); o0.w=__expf(leaky(a0.w+b0.w));
    o1.x=__expf(leaky(a1.x+b1.x)); o1.y=__expf(leaky(a1.y+b1.y));
    o1.z=__expf(leaky(a1.z+b1.z)); o1.w=__expf(leaky(a1.w+b1.w));
    float4* W = (float4*)(w1 + (size_t)e*H1);
    W[0]=o0; W[1]=o1;
}

// ---------------------------------------------------------------- layer1 aggregation: one wave per node, streaming
__global__ __launch_bounds__(256) void k_agg1(
        const int* __restrict__ rowptr, const int* __restrict__ srcs,
        const float* __restrict__ w1,
        const float* __restrict__ h1, float* __restrict__ out1){
    const int node = blockIdx.x*4 + (threadIdx.x>>6);
    const int c = threadIdx.x & 63;
    const int h = c >> 3;
    const int r0 = __builtin_amdgcn_readfirstlane(rowptr[node]);
    const int r1 = __builtin_amdgcn_readfirstlane(rowptr[node+1]);
    float acc = 0.f, den = 0.f;
    #pragma unroll 4
    for (int j=r0; j<r1; j++){
        int s   = srcs[j];                       // wave-uniform (scalar)
        float w = w1[(size_t)j*H1 + h];          // one 32B line / wave
        acc += w * h1[(size_t)s*D1 + c];
        den += w;
    }
    out1[(size_t)node*D1 + c] = acc/den;
}

// ---------------------------------------------------------------- GEMM2: h2 = elu(out1+b1) @ W2, + alpha projections
#define NPB2 8
__global__ __launch_bounds__(128) void k_gemm2(
        const float* __restrict__ out1, const float* __restrict__ b1,
        const float* __restrict__ W2,
        const float* __restrict__ att_src2, const float* __restrict__ att_dst2,
        float* __restrict__ h2, float* __restrict__ asrc2, float* __restrict__ adst2){
    __shared__ float W2s[D1*OUT_C];          // 32 KB
    __shared__ float xs[NPB2*D1];            // 2 KB
    __shared__ float red[2][NPB2][2];
    const int tid = threadIdx.x;
    const int n0  = blockIdx.x*NPB2;

    for (int i=tid; i<D1*OUT_C/4; i+=128) ((float4*)W2s)[i] = ((const float4*)W2)[i];
    for (int i=tid; i<NPB2*D1; i+=128){
        int c = i & (D1-1);
        float v = out1[(size_t)n0*D1 + i] + b1[c];
        xs[i] = v > 0.f ? v : (__expf(v) - 1.f);   // ELU
    }
    __syncthreads();

    const int col = tid;                     // 0..127
    float acc[NPB2];
    #pragma unroll
    for (int i=0;i<NPB2;i++) acc[i]=0.f;
    for (int k=0;k<D1;k++){
        float w = W2s[k*OUT_C + col];
        #pragma unroll
        for (int i=0;i<NPB2;i++) acc[i] += xs[i*D1+k]*w;
    }

    const float aw = att_src2[col], dw = att_dst2[col];
    const int wv = tid >> 6, lane = tid & 63;
    #pragma unroll
    for (int i=0;i<NPB2;i++){
        h2[(size_t)(n0+i)*OUT_C + col] = acc[i];
        float s = acc[i]*aw, d = acc[i]*dw;
        #pragma unroll
        for (int off=1; off<64; off<<=1){
            s += __shfl_xor(s, off);
            d += __shfl_xor(d, off);
        }
        if (lane == 0){ red[wv][i][0]=s; red[wv][i][1]=d; }
    }
    __syncthreads();
    if (tid < NPB2){
        asrc2[n0+tid] = red[0][tid][0] + red[1][tid][0];
        adst2[n0+tid] = red[0][tid][1] + red[1][tid][1];
    }
}

// ---------------------------------------------------------------- layer2 edge weights, packed (src, w) per slot
__global__ void k_w2(const int* __restrict__ srcs, const int* __restrict__ dsts, int ET,
                     const float* __restrict__ asrc2, const float* __restrict__ adst2,
                     int2* __restrict__ pw){
    int e = blockIdx.x*blockDim.x + threadIdx.x;
    if (e >= ET) return;
    int s = srcs[e], d = dsts[e];
    float w = __expf(leaky(asrc2[s] + adst2[d]));
    pw[e] = make_int2(s, __float_as_int(w));
}

// ---------------------------------------------------------------- layer2 aggregation: one wave per node, float2/lane
__global__ __launch_bounds__(256) void k_agg2(
        const int* __restrict__ rowptr, const int2* __restrict__ pw,
        const float* __restrict__ h2, const float* __restrict__ b2,
        float* __restrict__ out){
    const int node = blockIdx.x*4 + (threadIdx.x>>6);
    const int lane = threadIdx.x & 63;
    const int r0 = __builtin_amdgcn_readfirstlane(rowptr[node]);
    const int r1 = __builtin_amdgcn_readfirstlane(rowptr[node+1]);
    const float2* __restrict__ h2v = (const float2*)h2;   // row stride 64
    float ax = 0.f, ay = 0.f, den = 0.f;
    #pragma unroll 4
    for (int j=r0; j<r1; j++){
        int2 p = pw[j];                          // wave-uniform 8B
        float w = __int_as_float(p.y);
        float2 v = h2v[(size_t)p.x*64 + lane];
        ax += w*v.x; ay += w*v.y; den += w;
    }
    float inv = 1.f/den;
    float2 bb = ((const float2*)b2)[lane];
    float2 o; o.x = ax*inv + bb.x; o.y = ay*inv + bb.y;
    *(float2*)&out[(size_t)node*OUT_C + lane*2] = o;
}

// ---------------------------------------------------------------- launch
extern "C" void kernel_launch(void* const* d_in, const int* in_sizes, int n_in,
                              void* d_out, int out_size, void* d_ws, size_t ws_size,
                              hipStream_t stream) {
    const float* x        = (const float*)d_in[0];
    const int*   edge     = (const int*)  d_in[1];
    const float* W1       = (const float*)d_in[2];
    const float* att_src1 = (const float*)d_in[3];
    const float* att_dst1 = (const float*)d_in[4];
    const float* b1       = (const float*)d_in[5];
    const float* W2       = (const float*)d_in[6];
    const float* att_src2 = (const float*)d_in[7];
    const float* att_dst2 = (const float*)d_in[8];
    const float* b2       = (const float*)d_in[9];
    float* out = (float*)d_out;

    const int E  = in_sizes[1] / 2;
    const int ET = E + N_NODES;
    const int* src_a = edge;
    const int* dst_a = edge + E;

    // workspace layout
    float* ws = (float*)d_ws;
    float* h1    = ws;                            // N*64
    float* asrc1 = h1    + (size_t)N_NODES*D1;    // N*8
    float* adst1 = asrc1 + (size_t)N_NODES*H1;    // N*8
    float* out1  = adst1 + (size_t)N_NODES*H1;    // N*64
    float* h2    = out1  + (size_t)N_NODES*D1;    // N*128
    float* asrc2 = h2    + (size_t)N_NODES*OUT_C; // N
    float* adst2 = asrc2 + N_NODES;               // N
    int*   cnt    = (int*)(adst2 + N_NODES);      // N
    int*   rowptr = cnt    + N_NODES;             // N+1
    int*   cur    = rowptr + (N_NODES+1);         // N
    int*   srcs   = cur    + N_NODES;             // ET
    int*   dsts   = srcs   + ET;                  // ET
    int*   bsum   = dsts   + ET;                  // 256
    int*   boff   = bsum   + 256;                 // 256
    float* w1     = (float*)(boff + 256);         // ET*8
    int2*  pw     = (int2*)w1;                    // overlays w1 (dead after agg1)

    // ---- CSR build (counting sort by dst)
    hipLaunchKernelGGL(k_zero_cnt, dim3((N_NODES+255)/256), dim3(256), 0, stream, cnt);
    hipLaunchKernelGGL(k_hist,  dim3((E+255)/256), dim3(256), 0, stream, dst_a, E, cnt);
    hipLaunchKernelGGL(k_scanA, dim3(SNBLK), dim3(256), 0, stream, cnt, bsum);
    hipLaunchKernelGGL(k_scanB, dim3(1), dim3(256), 0, stream, bsum, boff, rowptr);
    hipLaunchKernelGGL(k_scanC, dim3(SNBLK), dim3(256), 0, stream, cnt, boff, rowptr, cur);
    hipLaunchKernelGGL(k_scatter, dim3((ET+255)/256), dim3(256), 0, stream,
                       src_a, dst_a, E, cur, srcs, dsts);

    // ---- layer 1
    hipLaunchKernelGGL(k_gemm1, dim3(N_NODES/NPB1), dim3(64), 0, stream,
                       x, W1, att_src1, att_dst1, h1, asrc1, adst1);
    hipLaunchKernelGGL(k_w1, dim3((ET+255)/256), dim3(256), 0, stream,
                       srcs, dsts, ET, asrc1, adst1, w1);
    hipLaunchKernelGGL(k_agg1, dim3(N_NODES/4), dim3(256), 0, stream,
                       rowptr, srcs, w1, h1, out1);

    // ---- layer 2
    hipLaunchKernelGGL(k_gemm2, dim3(N_NODES/NPB2), dim3(128), 0, stream,
                       out1, b1, W2, att_src2, att_dst2, h2, asrc2, adst2);
    hipLaunchKernelGGL(k_w2, dim3((ET+255)/256), dim3(256), 0, stream,
                       srcs, dsts, ET, asrc2, adst2, pw);
    hipLaunchKernelGGL(k_agg2, dim3(N_NODES/4), dim3(256), 0, stream,
                       rowptr, pw, h2, b2, out);
}

// Round 5
// 537.064 us; speedup vs baseline: 27.8658x; 1.0389x over previous
//
#include <hip/hip_runtime.h>
#include <math.h>

#define N_NODES 50000
#define F_IN    512
#define H1      8
#define C1      8
#define D1      64    // H1*C1
#define OUT_C   128
#define NEG     0.2f

#define SCHUNK  256
#define SNBLK   ((N_NODES + SCHUNK - 1)/SCHUNK)   // 196

using bf16x8 = __attribute__((ext_vector_type(8))) short;
using f32x4  = __attribute__((ext_vector_type(4))) float;
typedef unsigned short u16;
typedef unsigned int   u32;

__device__ __forceinline__ float leaky(float x){
    return fmaxf(x, 0.f) + NEG * fminf(x, 0.f);
}
__device__ __forceinline__ u16 f2bf(float f){           // RNE
    u32 u = __float_as_uint(f);
    u32 r = u + 0x7FFF + ((u>>16)&1);
    return (u16)(r>>16);
}
__device__ __forceinline__ float bf2f(u16 h){ return __uint_as_float(((u32)h)<<16); }

// ---------------------------------------------------------------- counts (self-loop => start at 1)
__global__ void k_zero_cnt(int* cnt){
    int i = blockIdx.x*blockDim.x + threadIdx.x;
    if (i < N_NODES) cnt[i] = 1;
}

__global__ void k_hist(const int* __restrict__ dst_a, int E, int* cnt){
    int i = blockIdx.x*blockDim.x + threadIdx.x;
    if (i >= E) return;
    atomicAdd(cnt + dst_a[i], 1);
}

// ---------------------------------------------------------------- 3-phase scan
__global__ __launch_bounds__(256) void k_scanA(const int* __restrict__ cnt, int* bsum){
    __shared__ int sm[256];
    int idx = blockIdx.x*256 + threadIdx.x;
    int v = (idx < N_NODES) ? cnt[idx] : 0;
    sm[threadIdx.x] = v; __syncthreads();
    for (int off=128; off>0; off>>=1){
        if (threadIdx.x < off) sm[threadIdx.x] += sm[threadIdx.x+off];
        __syncthreads();
    }
    if (threadIdx.x==0) bsum[blockIdx.x] = sm[0];
}

__global__ __launch_bounds__(256) void k_scanB(const int* __restrict__ bsum, int* boff, int* rowptr){
    __shared__ int sm[256];
    int t = threadIdx.x;
    int v = (t < SNBLK) ? bsum[t] : 0;
    sm[t]=v; __syncthreads();
    for (int off=1; off<256; off<<=1){
        int u = (t>=off)? sm[t-off] : 0;
        __syncthreads();
        sm[t]+=u; __syncthreads();
    }
    if (t < SNBLK) boff[t] = sm[t] - v;       // exclusive
    if (t==255) rowptr[N_NODES] = sm[255];    // total = E + N
}

__global__ __launch_bounds__(256) void k_scanC(const int* __restrict__ cnt, const int* __restrict__ boff,
                                               int* rowptr, int* cur){
    __shared__ int sm[256];
    int idx = blockIdx.x*256 + threadIdx.x;
    int t = threadIdx.x;
    int v = (idx<N_NODES)? cnt[idx] : 0;
    sm[t]=v; __syncthreads();
    for (int off=1; off<256; off<<=1){
        int u = (t>=off)? sm[t-off] : 0;
        __syncthreads();
        sm[t]+=u; __syncthreads();
    }
    if (idx<N_NODES){
        int ex = boff[blockIdx.x] + sm[t] - v;
        rowptr[idx]=ex; cur[idx]=ex;
    }
}

// ---------------------------------------------------------------- scatter edges + self-loops into CSR (src AND dst per slot)
__global__ void k_scatter(const int* __restrict__ src_a, const int* __restrict__ dst_a,
                          int E, int* cur, int* srcs, int* dsts){
    int i = blockIdx.x*blockDim.x + threadIdx.x;
    int ET = E + N_NODES;
    if (i >= ET) return;
    int s, d;
    if (i < E){ s = src_a[i]; d = dst_a[i]; }
    else      { s = d = i - E; }
    int pos = atomicAdd(cur + d, 1);
    srcs[pos] = s; dsts[pos] = d;
}

// ---------------------------------------------------------------- W1 split/transpose: whiT/wloT [64 col][512 k] bf16
__global__ void k_cvtW(const float* __restrict__ W1, u16* __restrict__ whiT, u16* __restrict__ wloT){
    int i = blockIdx.x*blockDim.x + threadIdx.x;   // 0..32767
    if (i >= F_IN*D1) return;
    int k = i >> 6, col = i & 63;
    float v = W1[i];
    u16 hi = f2bf(v);
    float lo = v - bf2f(hi);
    whiT[col*F_IN + k] = hi;
    wloT[col*F_IN + k] = f2bf(lo);
}

// ---------------------------------------------------------------- GEMM1 via MFMA (split-bf16, f32-accurate)
// block: 256 thr = 4 waves; tile 64 nodes x 64 cols; K step 64
__global__ __launch_bounds__(256) void k_gemm1(
        const float* __restrict__ x,
        const u16* __restrict__ whiT, const u16* __restrict__ wloT,
        const float* __restrict__ att_src, const float* __restrict__ att_dst,
        float* __restrict__ h1, float* __restrict__ asrc, float* __restrict__ adst){
    __shared__ u16 Ahi[64*64];   // 8 KB, XOR-swizzled [row][k]
    __shared__ u16 Alo[64*64];   // 8 KB
    const int tid = threadIdx.x;
    const int wid = tid>>6, l = tid&63;
    const int lq = l>>4, lr = l&15;
    const int rowbase = blockIdx.x*64;

    f32x4 acc[4];
    #pragma unroll
    for (int n=0;n<4;n++) acc[n] = (f32x4){0.f,0.f,0.f,0.f};

    for (int ks=0; ks<8; ks++){
        const int k0 = ks*64;
        __syncthreads();
        #pragma unroll
        for (int q=0;q<4;q++){
            int p = tid + 256*q;
            int r = p>>4, kseg = p&15;
            int grow = min(rowbase + r, N_NODES-1);
            float4 v = *(const float4*)(x + (size_t)grow*F_IN + k0 + kseg*4);
            u16 h0=f2bf(v.x), h1v=f2bf(v.y), h2v=f2bf(v.z), h3v=f2bf(v.w);
            u16 e0=f2bf(v.x-bf2f(h0)), e1=f2bf(v.y-bf2f(h1v)),
                e2=f2bf(v.z-bf2f(h2v)), e3=f2bf(v.w-bf2f(h3v));
            int boff = (r*128 + kseg*8) ^ ((r&7)<<4);
            *(ushort4*)((char*)Ahi + boff) = make_ushort4(h0,h1v,h2v,h3v);
            *(ushort4*)((char*)Alo + boff) = make_ushort4(e0,e1,e2,e3);
        }
        __syncthreads();

        const int arow = wid*16 + lr;
        bf16x8 ahi[2], alo[2];
        #pragma unroll
        for (int kt=0;kt<2;kt++){
            int boff = (arow*128 + kt*64 + lq*16) ^ ((arow&7)<<4);
            ahi[kt] = *(const bf16x8*)((const char*)Ahi + boff);
            alo[kt] = *(const bf16x8*)((const char*)Alo + boff);
        }
        #pragma unroll
        for (int n=0;n<4;n++){
            #pragma unroll
            for (int kt=0;kt<2;kt++){
                const size_t wo = (size_t)(n*16+lr)*F_IN + k0 + kt*32 + lq*8;
                bf16x8 bhi = *(const bf16x8*)(whiT + wo);
                bf16x8 blo = *(const bf16x8*)(wloT + wo);
                acc[n] = __builtin_amdgcn_mfma_f32_16x16x32_bf16(ahi[kt], bhi, acc[n], 0,0,0);
                acc[n] = __builtin_amdgcn_mfma_f32_16x16x32_bf16(ahi[kt], blo, acc[n], 0,0,0);
                acc[n] = __builtin_amdgcn_mfma_f32_16x16x32_bf16(alo[kt], bhi, acc[n], 0,0,0);
            }
        }
    }

    // epilogue: C/D layout col=lane&15, row=(lane>>4)*4+i  [HW-verified]
    #pragma unroll
    for (int n=0;n<4;n++){
        int col = n*16 + lr;
        float as_w = att_src[col], ad_w = att_dst[col];
        #pragma unroll
        for (int i=0;i<4;i++){
            int node = rowbase + wid*16 + lq*4 + i;
            float v = acc[n][i];
            float s = v*as_w, d = v*ad_w;
            s += __shfl_xor(s,1); d += __shfl_xor(d,1);
            s += __shfl_xor(s,2); d += __shfl_xor(d,2);
            s += __shfl_xor(s,4); d += __shfl_xor(d,4);
            if (node < N_NODES){
                h1[(size_t)node*D1 + col] = v;
                if ((l&7)==0){
                    int head = col>>3;
                    asrc[node*H1 + head] = s;
                    adst[node*H1 + head] = d;
                }
            }
        }
    }
}

// ---------------------------------------------------------------- layer1 edge weights (edge-parallel, coalesced)
__global__ void k_w1(const int* __restrict__ srcs, const int* __restrict__ dsts, int ET,
                     const float* __restrict__ asrc1, const float* __restrict__ adst1,
                     float* __restrict__ w1){
    int e = blockIdx.x*blockDim.x + threadIdx.x;
    if (e >= ET) return;
    int s = srcs[e], d = dsts[e];
    const float4* A = (const float4*)(asrc1 + (size_t)s*H1);
    const float4* B = (const float4*)(adst1 + (size_t)d*H1);
    float4 a0=A[0], a1=A[1], b0=B[0], b1=B[1];
    float4 o0, o1;
    o0.x=__expf(leaky(a0.x+b0.x)); o0.y=__expf(leaky(a0.y+b0.y));
    o0.z=__expf(leaky(a0.z+b0.z)); o0.w=__expf(leaky(a0.w+b0.w));
    o1.x=__expf(leaky(a1.x+b1.x)); o1.y=__expf(leaky(a1.y+b1.y));
    o1.z=__expf(leaky(a1.z+b1.z)); o1.w=__expf(leaky(a1.w+b1.w));
    float4* W = (float4*)(w1 + (size_t)e*H1);
    W[0]=o0; W[1]=o1;
}

// ---------------------------------------------------------------- layer1 aggregation: one wave per node, streaming
__global__ __launch_bounds__(256) void k_agg1(
        const int* __restrict__ rowptr, const int* __restrict__ srcs,
        const float* __restrict__ w1,
        const float* __restrict__ h1, float* __restrict__ out1){
    const int node = blockIdx.x*4 + (threadIdx.x>>6);
    const int c = threadIdx.x & 63;
    const int h = c >> 3;
    const int r0 = __builtin_amdgcn_readfirstlane(rowptr[node]);
    const int r1 = __builtin_amdgcn_readfirstlane(rowptr[node+1]);
    float acc = 0.f, den = 0.f;
    #pragma unroll 4
    for (int j=r0; j<r1; j++){
        int s   = srcs[j];                       // wave-uniform (scalar)
        float w = w1[(size_t)j*H1 + h];          // one 32B line / wave
        acc += w * h1[(size_t)s*D1 + c];
        den += w;
    }
    out1[(size_t)node*D1 + c] = acc/den;
}

// ---------------------------------------------------------------- GEMM2: h2 = elu(out1+b1) @ W2, + alpha projections
#define NPB2 8
__global__ __launch_bounds__(128) void k_gemm2(
        const float* __restrict__ out1, const float* __restrict__ b1,
        const float* __restrict__ W2,
        const float* __restrict__ att_src2, const float* __restrict__ att_dst2,
        float* __restrict__ h2, float* __restrict__ asrc2, float* __restrict__ adst2){
    __shared__ float W2s[D1*OUT_C];          // 32 KB
    __shared__ float xs[NPB2*D1];            // 2 KB
    __shared__ float red[2][NPB2][2];
    const int tid = threadIdx.x;
    const int n0  = blockIdx.x*NPB2;

    for (int i=tid; i<D1*OUT_C/4; i+=128) ((float4*)W2s)[i] = ((const float4*)W2)[i];
    for (int i=tid; i<NPB2*D1; i+=128){
        int c = i & (D1-1);
        float v = out1[(size_t)n0*D1 + i] + b1[c];
        xs[i] = v > 0.f ? v : (__expf(v) - 1.f);   // ELU
    }
    __syncthreads();

    const int col = tid;                     // 0..127
    float acc[NPB2];
    #pragma unroll
    for (int i=0;i<NPB2;i++) acc[i]=0.f;
    for (int k=0;k<D1;k++){
        float w = W2s[k*OUT_C + col];
        #pragma unroll
        for (int i=0;i<NPB2;i++) acc[i] += xs[i*D1+k]*w;
    }

    const float aw = att_src2[col], dw = att_dst2[col];
    const int wv = tid >> 6, lane = tid & 63;
    #pragma unroll
    for (int i=0;i<NPB2;i++){
        h2[(size_t)(n0+i)*OUT_C + col] = acc[i];
        float s = acc[i]*aw, d = acc[i]*dw;
        #pragma unroll
        for (int off=1; off<64; off<<=1){
            s += __shfl_xor(s, off);
            d += __shfl_xor(d, off);
        }
        if (lane == 0){ red[wv][i][0]=s; red[wv][i][1]=d; }
    }
    __syncthreads();
    if (tid < NPB2){
        asrc2[n0+tid] = red[0][tid][0] + red[1][tid][0];
        adst2[n0+tid] = red[0][tid][1] + red[1][tid][1];
    }
}

// ---------------------------------------------------------------- layer2 edge weights, packed (src, w) per slot
__global__ void k_w2(const int* __restrict__ srcs, const int* __restrict__ dsts, int ET,
                     const float* __restrict__ asrc2, const float* __restrict__ adst2,
                     int2* __restrict__ pw){
    int e = blockIdx.x*blockDim.x + threadIdx.x;
    if (e >= ET) return;
    int s = srcs[e], d = dsts[e];
    float w = __expf(leaky(asrc2[s] + adst2[d]));
    pw[e] = make_int2(s, __float_as_int(w));
}

// ---------------------------------------------------------------- layer2 aggregation: one wave per node, float2/lane
__global__ __launch_bounds__(256) void k_agg2(
        const int* __restrict__ rowptr, const int2* __restrict__ pw,
        const float* __restrict__ h2, const float* __restrict__ b2,
        float* __restrict__ out){
    const int node = blockIdx.x*4 + (threadIdx.x>>6);
    const int lane = threadIdx.x & 63;
    const int r0 = __builtin_amdgcn_readfirstlane(rowptr[node]);
    const int r1 = __builtin_amdgcn_readfirstlane(rowptr[node+1]);
    const float2* __restrict__ h2v = (const float2*)h2;   // row stride 64
    float ax = 0.f, ay = 0.f, den = 0.f;
    #pragma unroll 4
    for (int j=r0; j<r1; j++){
        int2 p = pw[j];                          // wave-uniform 8B
        float w = __int_as_float(p.y);
        float2 v = h2v[(size_t)p.x*64 + lane];
        ax += w*v.x; ay += w*v.y; den += w;
    }
    float inv = 1.f/den;
    float2 bb = ((const float2*)b2)[lane];
    float2 o; o.x = ax*inv + bb.x; o.y = ay*inv + bb.y;
    *(float2*)&out[(size_t)node*OUT_C + lane*2] = o;
}

// ---------------------------------------------------------------- launch
extern "C" void kernel_launch(void* const* d_in, const int* in_sizes, int n_in,
                              void* d_out, int out_size, void* d_ws, size_t ws_size,
                              hipStream_t stream) {
    const float* x        = (const float*)d_in[0];
    const int*   edge     = (const int*)  d_in[1];
    const float* W1       = (const float*)d_in[2];
    const float* att_src1 = (const float*)d_in[3];
    const float* att_dst1 = (const float*)d_in[4];
    const float* b1       = (const float*)d_in[5];
    const float* W2       = (const float*)d_in[6];
    const float* att_src2 = (const float*)d_in[7];
    const float* att_dst2 = (const float*)d_in[8];
    const float* b2       = (const float*)d_in[9];
    float* out = (float*)d_out;

    const int E  = in_sizes[1] / 2;
    const int ET = E + N_NODES;
    const int* src_a = edge;
    const int* dst_a = edge + E;

    // workspace layout
    float* ws = (float*)d_ws;
    float* h1    = ws;                            // N*64
    float* asrc1 = h1    + (size_t)N_NODES*D1;    // N*8
    float* adst1 = asrc1 + (size_t)N_NODES*H1;    // N*8
    float* out1  = adst1 + (size_t)N_NODES*H1;    // N*64
    float* h2    = out1  + (size_t)N_NODES*D1;    // N*128
    float* asrc2 = h2    + (size_t)N_NODES*OUT_C; // N
    float* adst2 = asrc2 + N_NODES;               // N
    int*   cnt    = (int*)(adst2 + N_NODES);      // N
    int*   rowptr = cnt    + N_NODES;             // N+4 (padded for 16B alignment of cur)
    int*   cur    = rowptr + (N_NODES+4);         // N  (reused as whiT/wloT after scatter)
    int*   srcs   = cur    + N_NODES;             // ET
    int*   dsts   = srcs   + ET;                  // ET
    int*   bsum   = dsts   + ET;                  // 256
    int*   boff   = bsum   + 256;                 // 256
    float* w1     = (float*)(boff + 256);         // ET*8
    int2*  pw     = (int2*)w1;                    // overlays w1 (dead after agg1)
    u16*   whiT   = (u16*)cur;                    // 64*512 (overlays cur after scatter)
    u16*   wloT   = whiT + F_IN*D1;               // 64*512

    // ---- CSR build (counting sort by dst)
    hipLaunchKernelGGL(k_zero_cnt, dim3((N_NODES+255)/256), dim3(256), 0, stream, cnt);
    hipLaunchKernelGGL(k_hist,  dim3((E+255)/256), dim3(256), 0, stream, dst_a, E, cnt);
    hipLaunchKernelGGL(k_scanA, dim3(SNBLK), dim3(256), 0, stream, cnt, bsum);
    hipLaunchKernelGGL(k_scanB, dim3(1), dim3(256), 0, stream, bsum, boff, rowptr);
    hipLaunchKernelGGL(k_scanC, dim3(SNBLK), dim3(256), 0, stream, cnt, boff, rowptr, cur);
    hipLaunchKernelGGL(k_scatter, dim3((ET+255)/256), dim3(256), 0, stream,
                       src_a, dst_a, E, cur, srcs, dsts);

    // ---- layer 1
    hipLaunchKernelGGL(k_cvtW, dim3((F_IN*D1+255)/256), dim3(256), 0, stream,
                       W1, whiT, wloT);
    hipLaunchKernelGGL(k_gemm1, dim3((N_NODES+63)/64), dim3(256), 0, stream,
                       x, whiT, wloT, att_src1, att_dst1, h1, asrc1, adst1);
    hipLaunchKernelGGL(k_w1, dim3((ET+255)/256), dim3(256), 0, stream,
                       srcs, dsts, ET, asrc1, adst1, w1);
    hipLaunchKernelGGL(k_agg1, dim3(N_NODES/4), dim3(256), 0, stream,
                       rowptr, srcs, w1, h1, out1);

    // ---- layer 2
    hipLaunchKernelGGL(k_gemm2, dim3(N_NODES/NPB2), dim3(128), 0, stream,
                       out1, b1, W2, att_src2, att_dst2, h2, asrc2, adst2);
    hipLaunchKernelGGL(k_w2, dim3((ET+255)/256), dim3(256), 0, stream,
                       srcs, dsts, ET, asrc2, adst2, pw);
    hipLaunchKernelGGL(k_agg2, dim3(N_NODES/4), dim3(256), 0, stream,
                       rowptr, pw, h2, b2, out);
}